// Round 1
// baseline (205.677 us; speedup 1.0000x reference)
//
#include <hip/hip_runtime.h>
#include <math.h>

// DigitalGCN: B=16, N=1024, D=128, 2 iterations, fp32.
// Rewritten: left+right = nm_i*[ (Vtot - v_i) + (G@x)_i - g_ii*x_i ],
//   x = nm*w*(N@Wl - N@Wr), v = nm*w*(N@Wr), nnum = max(nm_i*(S_b-nm_i),1).
// Heavy op: batched G[1024x1024] @ x[1024x128] per batch, fp32 VALU.

constexpr int B = 16, N = 1024, D = 128, ITERS = 2;

__global__ __launch_bounds__(256) void mask_sum_kernel(const int* __restrict__ mask,
                                                       float* __restrict__ sb) {
  __shared__ float red[256];
  int b = blockIdx.x;
  float s = 0.f;
  for (int j = threadIdx.x; j < N; j += 256) s += (float)mask[b * N + j];
  red[threadIdx.x] = s;
  __syncthreads();
  for (int off = 128; off > 0; off >>= 1) {
    if (threadIdx.x < off) red[threadIdx.x] += red[threadIdx.x + off];
    __syncthreads();
  }
  if (threadIdx.x == 0) sb[b] = red[0];
}

// prep: per 32-row tile of one batch: node_weight (sigmoid), NS = node@Wself+b,
// NL, NR; store ns, x = nmw*(NL-NR), v = nmw*NR; deterministic per-tile V partial.
__global__ __launch_bounds__(256) void prep_kernel(
    const float* __restrict__ node, const int* __restrict__ mask,
    const float* __restrict__ w_weight, const float* __restrict__ b_weight,
    const float* __restrict__ w_self, const float* __restrict__ b_self,
    const float* __restrict__ w_left, const float* __restrict__ w_right,
    float* __restrict__ outw_t,  // d_out weight region + t*N; index b*(2N)+i
    float* __restrict__ xbuf, float* __restrict__ vbuf, float* __restrict__ nsbuf,
    float* __restrict__ part)    // [B*32][128] per-tile partial of v-sum
{
  __shared__ float nl[32][128];   // node tile, 16 KB
  __shared__ float wl[32][128];   // W K-chunk, 16 KB (also reused as reduce buf)
  __shared__ float wrow[32];      // node_weight per row
  int tid = threadIdx.x;
  int b = blockIdx.x >> 5;
  int rtile = blockIdx.x & 31;
  int r0 = rtile * 32;
  int ty = tid >> 5, tx = tid & 31;

  const float* nbase = node + ((size_t)b * N + r0) * D;
#pragma unroll
  for (int p = 0; p < 4; ++p) {
    int idx = p * 256 + tid;
    ((float4*)&nl[0][0])[idx] = ((const float4*)nbase)[idx];
  }

  // node_weight: 8 threads per row, straight from global (coalesced), shfl-reduce
  {
    int r = tid >> 3, j = tid & 7;
    const float* nr = nbase + (size_t)r * D + j * 16;
    float acc = 0.f;
#pragma unroll
    for (int q = 0; q < 4; ++q) {
      float4 nv = *(const float4*)(nr + q * 4);
      float4 wv = *(const float4*)(w_weight + j * 16 + q * 4);
      acc += nv.x * wv.x + nv.y * wv.y + nv.z * wv.z + nv.w * wv.w;
    }
    acc += __shfl_down(acc, 4, 8);
    acc += __shfl_down(acc, 2, 8);
    acc += __shfl_down(acc, 1, 8);
    if (j == 0) {
      float w = 1.f / (1.f + expf(-(acc + b_weight[0])));
      wrow[r] = w;
      outw_t[b * (ITERS * N) + r0 + r] = w;
    }
  }

  float accA[4][4], accB[4][4];

  auto run_gemm = [&](const float* __restrict__ W, float (&acc)[4][4]) {
#pragma unroll
    for (int u = 0; u < 4; ++u)
#pragma unroll
      for (int c = 0; c < 4; ++c) acc[u][c] = 0.f;
    for (int k0 = 0; k0 < 128; k0 += 32) {
      __syncthreads();  // wl safe to overwrite (also covers nl staging on 1st pass)
#pragma unroll
      for (int p = 0; p < 4; ++p) {
        int idx = p * 256 + tid;
        ((float4*)&wl[0][0])[idx] = ((const float4*)(W + (size_t)k0 * D))[idx];
      }
      __syncthreads();
#pragma unroll
      for (int k = 0; k < 32; k += 4) {
        float a[4][4];
#pragma unroll
        for (int u = 0; u < 4; ++u)
          *(float4*)&a[u][0] = *(const float4*)&nl[ty * 4 + u][k0 + k];
#pragma unroll
        for (int kk = 0; kk < 4; ++kk) {
          float bv[4];
          *(float4*)&bv[0] = *(const float4*)&wl[k + kk][tx * 4];
#pragma unroll
          for (int u = 0; u < 4; ++u)
#pragma unroll
            for (int c = 0; c < 4; ++c) acc[u][c] += a[u][kk] * bv[c];
        }
      }
    }
  };

  run_gemm(w_self, accA);
  {
    float bs[4];
    *(float4*)&bs[0] = *(const float4*)(b_self + tx * 4);
#pragma unroll
    for (int u = 0; u < 4; ++u) {
      int i = r0 + ty * 4 + u;
      float o[4];
#pragma unroll
      for (int c = 0; c < 4; ++c) o[c] = accA[u][c] + bs[c];
      *(float4*)&nsbuf[((size_t)b * N + i) * D + tx * 4] = *(float4*)&o[0];
    }
  }
  run_gemm(w_left, accA);   // NL
  run_gemm(w_right, accB);  // NR

  float pv[4] = {0.f, 0.f, 0.f, 0.f};
#pragma unroll
  for (int u = 0; u < 4; ++u) {
    int r = ty * 4 + u;
    int i = r0 + r;
    float nmw = (float)mask[b * N + i] * wrow[r];
    float xv[4], vv[4];
#pragma unroll
    for (int c = 0; c < 4; ++c) {
      float nr_ = accB[u][c];
      float vvv = nmw * nr_;
      vv[c] = vvv;
      xv[c] = nmw * (accA[u][c] - nr_);
      pv[c] += vvv;
    }
    size_t off = ((size_t)b * N + i) * D + tx * 4;
    *(float4*)&xbuf[off] = *(float4*)&xv[0];
    *(float4*)&vbuf[off] = *(float4*)&vv[0];
  }

  // deterministic per-tile v reduction (no atomics)
  __syncthreads();
  float* red = &wl[0][0];
#pragma unroll
  for (int c = 0; c < 4; ++c) red[ty * 128 + tx * 4 + c] = pv[c];
  __syncthreads();
  if (tid < 128) {
    float s = 0.f;
#pragma unroll
    for (int q = 0; q < 8; ++q) s += red[q * 128 + tid];
    part[((size_t)b * 32 + rtile) * 128 + tid] = s;
  }
}

__global__ __launch_bounds__(256) void vtot_kernel(const float* __restrict__ part,
                                                   float* __restrict__ vtot) {
  int idx = blockIdx.x * 256 + threadIdx.x;  // 0..2047
  int b = idx >> 7, dcol = idx & 127;
  float s = 0.f;
  for (int rt = 0; rt < 32; ++rt) s += part[((size_t)b * 32 + rt) * 128 + dcol];
  vtot[idx] = s;
}

// agg: M = G @ x (32-row tile, K-tiles of 32), fused epilogue:
// out = relu(ns + nm/nnum * (M + Vtot - v_i - g_ii*x_i))
__global__ __launch_bounds__(256) void agg_kernel(
    const int* __restrict__ graph, const int* __restrict__ mask,
    const float* __restrict__ xbuf, const float* __restrict__ vbuf,
    const float* __restrict__ nsbuf, const float* __restrict__ vtot,
    const float* __restrict__ sb, float* __restrict__ node_out) {
  __shared__ float gt[32][36];   // +4 pad keeps 16B alignment, spreads banks
  __shared__ float xt[32][128];
  int tid = threadIdx.x;
  int b = blockIdx.x >> 5;
  int r0 = (blockIdx.x & 31) * 32;
  int ty = tid >> 5, tx = tid & 31;
  float acc[4][4] = {};
  const int* gbase = graph + ((size_t)b * N + r0) * N;

  for (int k0 = 0; k0 < N; k0 += 32) {
    {
      int r = tid >> 3, q = tid & 7;
      int4 gi = *(const int4*)(gbase + (size_t)r * N + k0 + q * 4);
      gt[r][q * 4 + 0] = (float)gi.x;
      gt[r][q * 4 + 1] = (float)gi.y;
      gt[r][q * 4 + 2] = (float)gi.z;
      gt[r][q * 4 + 3] = (float)gi.w;
    }
#pragma unroll
    for (int p = 0; p < 4; ++p) {
      int idx = p * 256 + tid;
      int r = idx >> 5, c4 = idx & 31;
      *(float4*)&xt[r][c4 * 4] =
          *(const float4*)&xbuf[((size_t)b * N + k0 + r) * D + c4 * 4];
    }
    __syncthreads();
#pragma unroll
    for (int k = 0; k < 32; k += 4) {
      float a[4][4];
#pragma unroll
      for (int u = 0; u < 4; ++u)
        *(float4*)&a[u][0] = *(const float4*)&gt[ty * 4 + u][k];
#pragma unroll
      for (int kk = 0; kk < 4; ++kk) {
        float bv[4];
        *(float4*)&bv[0] = *(const float4*)&xt[k + kk][tx * 4];
#pragma unroll
        for (int u = 0; u < 4; ++u)
#pragma unroll
          for (int c = 0; c < 4; ++c) acc[u][c] += a[u][kk] * bv[c];
      }
    }
    __syncthreads();
  }

  float sbv = sb[b];
  float4 vt4 = *(const float4*)&vtot[b * D + tx * 4];
  float vt[4] = {vt4.x, vt4.y, vt4.z, vt4.w};
#pragma unroll
  for (int u = 0; u < 4; ++u) {
    int i = r0 + ty * 4 + u;
    float nm = (float)mask[b * N + i];
    float nnum = fmaxf(nm * (sbv - nm), 1.f);
    float gii = (float)graph[((size_t)b * N + i) * N + i];
    float inv = nm / nnum;
    size_t off = ((size_t)b * N + i) * D + tx * 4;
    float4 xi = *(const float4*)&xbuf[off];
    float4 vi = *(const float4*)&vbuf[off];
    float4 ns = *(const float4*)&nsbuf[off];
    float xia[4] = {xi.x, xi.y, xi.z, xi.w};
    float via[4] = {vi.x, vi.y, vi.z, vi.w};
    float nsa[4] = {ns.x, ns.y, ns.z, ns.w};
    float o[4];
#pragma unroll
    for (int c = 0; c < 4; ++c) {
      float m = acc[u][c] + vt[c] - via[c] - gii * xia[c];
      o[c] = fmaxf(nsa[c] + inv * m, 0.f);
    }
    *(float4*)&node_out[off] = *(float4*)&o[0];
  }
}

extern "C" void kernel_launch(void* const* d_in, const int* in_sizes, int n_in,
                              void* d_out, int out_size, void* d_ws, size_t ws_size,
                              hipStream_t stream) {
  const float* node0 = (const float*)d_in[0];
  const int* mask = (const int*)d_in[1];
  const int* graph = (const int*)d_in[2];
  const float* w_weight = (const float*)d_in[3];
  const float* b_weight = (const float*)d_in[4];
  const float* w_self = (const float*)d_in[5];
  const float* b_self = (const float*)d_in[6];
  const float* w_left = (const float*)d_in[7];
  const float* w_right = (const float*)d_in[8];
  float* out = (float*)d_out;
  float* outw = out + (size_t)B * N * D;  // all_node_weight region [B,2,N]

  float* f = (float*)d_ws;  // uses ~33.8 MB of workspace
  float* xbuf = f;
  float* vbuf = xbuf + (size_t)B * N * D;
  float* nsbuf = vbuf + (size_t)B * N * D;
  float* nbuf = nsbuf + (size_t)B * N * D;
  float* sb = nbuf + (size_t)B * N * D;
  float* part = sb + B;
  float* vtot = part + (size_t)B * 32 * 128;

  mask_sum_kernel<<<B, 256, 0, stream>>>(mask, sb);
  const float* cur = node0;
  for (int t = 0; t < ITERS; ++t) {
    float* nxt = (t == ITERS - 1) ? out : nbuf;
    prep_kernel<<<B * 32, 256, 0, stream>>>(cur, mask, w_weight, b_weight, w_self,
                                            b_self, w_left, w_right, outw + t * N,
                                            xbuf, vbuf, nsbuf, part);
    vtot_kernel<<<8, 256, 0, stream>>>(part, vtot);
    agg_kernel<<<B * 32, 256, 0, stream>>>(graph, mask, xbuf, vbuf, nsbuf, vtot, sb,
                                           nxt);
    cur = nxt;
  }
}

// Round 2
// 136.408 us; speedup vs baseline: 1.5078x; 1.5078x over previous
//
#include <hip/hip_runtime.h>
#include <math.h>

// DigitalGCN: B=16, N=1024, D=128, 2 iterations, fp32 in/out.
// left+right = nm_i*[ (Vtot - v_i) + (G@x)_i - g_ii*x_i ],
//   x = nm*w*(NL-NR), v = nm*w*NR, nnum = max(nm_i*(S_b-nm_i),1).
// G@x now runs on bf16 MFMA (G is 0/1 = exact in bf16; error /nnum ~ 5e-4).

constexpr int B = 16, N = 1024, D = 128, ITERS = 2;

typedef unsigned short u16;
typedef __attribute__((ext_vector_type(8))) short short8v;
typedef __attribute__((ext_vector_type(4))) float float4v;

__device__ inline u16 f32_to_bf16(float f) {
  unsigned int bits = __float_as_uint(f);
  bits += 0x7FFFu + ((bits >> 16) & 1u);  // RNE
  return (u16)(bits >> 16);
}

__global__ __launch_bounds__(256) void mask_sum_kernel(const int* __restrict__ mask,
                                                       float* __restrict__ sb) {
  __shared__ float red[256];
  int b = blockIdx.x;
  float s = 0.f;
  for (int j = threadIdx.x; j < N; j += 256) s += (float)mask[b * N + j];
  red[threadIdx.x] = s;
  __syncthreads();
  for (int off = 128; off > 0; off >>= 1) {
    if (threadIdx.x < off) red[threadIdx.x] += red[threadIdx.x + off];
    __syncthreads();
  }
  if (threadIdx.x == 0) sb[b] = red[0];
}

// prep: per 32-row tile: node_weight (sigmoid), NS = node@Wself+b, NL, NR;
// store ns, x=nmw*(NL-NR) (fp32 + bf16-transposed), v=nmw*NR; per-tile V partial.
__global__ __launch_bounds__(256) void prep_kernel(
    const float* __restrict__ node, const int* __restrict__ mask,
    const float* __restrict__ w_weight, const float* __restrict__ b_weight,
    const float* __restrict__ w_self, const float* __restrict__ b_self,
    const float* __restrict__ w_left, const float* __restrict__ w_right,
    float* __restrict__ outw_t, float* __restrict__ xbuf, float* __restrict__ vbuf,
    float* __restrict__ nsbuf, u16* __restrict__ xT, float* __restrict__ part) {
  __shared__ float nl[32][128];
  __shared__ float wl[32][128];
  __shared__ float wrow[32];
  int tid = threadIdx.x;
  int b = blockIdx.x >> 5;
  int rtile = blockIdx.x & 31;
  int r0 = rtile * 32;
  int ty = tid >> 5, tx = tid & 31;

  const float* nbase = node + ((size_t)b * N + r0) * D;
#pragma unroll
  for (int p = 0; p < 4; ++p) {
    int idx = p * 256 + tid;
    ((float4*)&nl[0][0])[idx] = ((const float4*)nbase)[idx];
  }

  {
    int r = tid >> 3, j = tid & 7;
    const float* nr = nbase + (size_t)r * D + j * 16;
    float acc = 0.f;
#pragma unroll
    for (int q = 0; q < 4; ++q) {
      float4 nv = *(const float4*)(nr + q * 4);
      float4 wv = *(const float4*)(w_weight + j * 16 + q * 4);
      acc += nv.x * wv.x + nv.y * wv.y + nv.z * wv.z + nv.w * wv.w;
    }
    acc += __shfl_down(acc, 4, 8);
    acc += __shfl_down(acc, 2, 8);
    acc += __shfl_down(acc, 1, 8);
    if (j == 0) {
      float w = 1.f / (1.f + expf(-(acc + b_weight[0])));
      wrow[r] = w;
      outw_t[b * (ITERS * N) + r0 + r] = w;
    }
  }

  float accA[4][4], accB[4][4];

  auto run_gemm = [&](const float* __restrict__ W, float (&acc)[4][4]) {
#pragma unroll
    for (int u = 0; u < 4; ++u)
#pragma unroll
      for (int c = 0; c < 4; ++c) acc[u][c] = 0.f;
    for (int k0 = 0; k0 < 128; k0 += 32) {
      __syncthreads();
#pragma unroll
      for (int p = 0; p < 4; ++p) {
        int idx = p * 256 + tid;
        ((float4*)&wl[0][0])[idx] = ((const float4*)(W + (size_t)k0 * D))[idx];
      }
      __syncthreads();
#pragma unroll
      for (int k = 0; k < 32; k += 4) {
        float a[4][4];
#pragma unroll
        for (int u = 0; u < 4; ++u)
          *(float4*)&a[u][0] = *(const float4*)&nl[ty * 4 + u][k0 + k];
#pragma unroll
        for (int kk = 0; kk < 4; ++kk) {
          float bv[4];
          *(float4*)&bv[0] = *(const float4*)&wl[k + kk][tx * 4];
#pragma unroll
          for (int u = 0; u < 4; ++u)
#pragma unroll
            for (int c = 0; c < 4; ++c) acc[u][c] += a[u][kk] * bv[c];
        }
      }
    }
  };

  run_gemm(w_self, accA);
  {
    float bs[4];
    *(float4*)&bs[0] = *(const float4*)(b_self + tx * 4);
#pragma unroll
    for (int u = 0; u < 4; ++u) {
      int i = r0 + ty * 4 + u;
      float o[4];
#pragma unroll
      for (int c = 0; c < 4; ++c) o[c] = accA[u][c] + bs[c];
      *(float4*)&nsbuf[((size_t)b * N + i) * D + tx * 4] = *(float4*)&o[0];
    }
  }
  run_gemm(w_left, accA);   // NL
  run_gemm(w_right, accB);  // NR

  float xv[4][4], vv[4][4];
  float pv[4] = {0.f, 0.f, 0.f, 0.f};
#pragma unroll
  for (int u = 0; u < 4; ++u) {
    int r = ty * 4 + u;
    int i = r0 + r;
    float nmw = (float)mask[b * N + i] * wrow[r];
#pragma unroll
    for (int c = 0; c < 4; ++c) {
      float nr_ = accB[u][c];
      float vvv = nmw * nr_;
      vv[u][c] = vvv;
      xv[u][c] = nmw * (accA[u][c] - nr_);
      pv[c] += vvv;
    }
    size_t off = ((size_t)b * N + i) * D + tx * 4;
    *(float4*)&xbuf[off] = *(float4*)&xv[u][0];
    *(float4*)&vbuf[off] = *(float4*)&vv[u][0];
  }

  // bf16 transposed x: xT[b][d][i]
#pragma unroll
  for (int c = 0; c < 4; ++c) {
    ushort4 q;
    q.x = f32_to_bf16(xv[0][c]);
    q.y = f32_to_bf16(xv[1][c]);
    q.z = f32_to_bf16(xv[2][c]);
    q.w = f32_to_bf16(xv[3][c]);
    *(ushort4*)&xT[((size_t)b * D + tx * 4 + c) * N + r0 + ty * 4] = q;
  }

  __syncthreads();
  float* red = &wl[0][0];
#pragma unroll
  for (int c = 0; c < 4; ++c) red[ty * 128 + tx * 4 + c] = pv[c];
  __syncthreads();
  if (tid < 128) {
    float s = 0.f;
#pragma unroll
    for (int q = 0; q < 8; ++q) s += red[q * 128 + tid];
    part[((size_t)b * 32 + rtile) * 128 + tid] = s;
  }
}

__global__ __launch_bounds__(256) void vtot_kernel(const float* __restrict__ part,
                                                   float* __restrict__ vtot) {
  int idx = blockIdx.x * 256 + threadIdx.x;
  int b = idx >> 7, dcol = idx & 127;
  float s = 0.f;
  for (int rt = 0; rt < 32; ++rt) s += part[((size_t)b * 32 + rt) * 128 + dcol];
  vtot[idx] = s;
}

// agg: M = G @ x via bf16 MFMA. MODE 0: int graph in, gbf out. 1: gbf in. 2: int, no write.
template <int MODE>
__global__ __launch_bounds__(256) void agg_mfma_kernel(
    const int* __restrict__ graph, u16* __restrict__ gbf, const u16* __restrict__ xT,
    const int* __restrict__ mask, const float* __restrict__ xbuf,
    const float* __restrict__ vbuf, const float* __restrict__ nsbuf,
    const float* __restrict__ vtot, const float* __restrict__ sb,
    float* __restrict__ node_out) {
  __shared__ u16 gt[32][88];  // 64 + 24 pad: 176B row stride, uniform 8-slot b128
  int tid = threadIdx.x;
  int b = blockIdx.x >> 5;
  int r0 = (blockIdx.x & 31) * 32;
  int w = tid >> 6, lane = tid & 63;
  int l15 = lane & 15, lg = lane >> 4;

  float4v acc[2][2] = {{{0.f, 0.f, 0.f, 0.f}, {0.f, 0.f, 0.f, 0.f}},
                       {{0.f, 0.f, 0.f, 0.f}, {0.f, 0.f, 0.f, 0.f}}};

  int srow = tid >> 3, skq = tid & 7;
  const size_t grow = ((size_t)b * N + r0 + srow) * N;
  const u16* xrow0 = xT + ((size_t)b * D + w * 32 + l15) * N;
  const u16* xrow1 = xrow0 + 16 * N;

  for (int k0 = 0; k0 < N; k0 += 64) {
    __syncthreads();
    {
      short8v pk;
      if (MODE != 1) {
        const int* gp = graph + grow + k0 + skq * 8;
        int4 i0 = *(const int4*)gp;
        int4 i1 = *(const int4*)(gp + 4);
        pk[0] = i0.x ? (short)0x3F80 : (short)0;
        pk[1] = i0.y ? (short)0x3F80 : (short)0;
        pk[2] = i0.z ? (short)0x3F80 : (short)0;
        pk[3] = i0.w ? (short)0x3F80 : (short)0;
        pk[4] = i1.x ? (short)0x3F80 : (short)0;
        pk[5] = i1.y ? (short)0x3F80 : (short)0;
        pk[6] = i1.z ? (short)0x3F80 : (short)0;
        pk[7] = i1.w ? (short)0x3F80 : (short)0;
        if (MODE == 0) *(short8v*)&gbf[grow + k0 + skq * 8] = pk;
      } else {
        pk = *(const short8v*)&gbf[grow + k0 + skq * 8];
      }
      *(short8v*)&gt[srow][skq * 8] = pk;
    }
    __syncthreads();
#pragma unroll
    for (int ks = 0; ks < 2; ++ks) {
      int kb = k0 + ks * 32 + lg * 8;
      short8v b0 = *(const short8v*)&xrow0[kb];
      short8v b1 = *(const short8v*)&xrow1[kb];
      short8v a0 = *(const short8v*)&gt[l15][ks * 32 + lg * 8];
      short8v a1 = *(const short8v*)&gt[16 + l15][ks * 32 + lg * 8];
      acc[0][0] = __builtin_amdgcn_mfma_f32_16x16x32_bf16(a0, b0, acc[0][0], 0, 0, 0);
      acc[0][1] = __builtin_amdgcn_mfma_f32_16x16x32_bf16(a0, b1, acc[0][1], 0, 0, 0);
      acc[1][0] = __builtin_amdgcn_mfma_f32_16x16x32_bf16(a1, b0, acc[1][0], 0, 0, 0);
      acc[1][1] = __builtin_amdgcn_mfma_f32_16x16x32_bf16(a1, b1, acc[1][1], 0, 0, 0);
    }
  }

  float sbv = sb[b];
  int colbase = w * 32 + l15;
  float vt[2];
  vt[0] = vtot[b * D + colbase];
  vt[1] = vtot[b * D + colbase + 16];
#pragma unroll
  for (int mr = 0; mr < 2; ++mr) {
#pragma unroll
    for (int j = 0; j < 4; ++j) {
      int i = r0 + mr * 16 + lg * 4 + j;
      float nm = (float)mask[b * N + i];
      float nnum = fmaxf(nm * (sbv - nm), 1.f);
      float inv = nm / nnum;
      float gii = (float)graph[((size_t)b * N + i) * N + i];
      size_t rowoff = ((size_t)b * N + i) * D;
#pragma unroll
      for (int nc = 0; nc < 2; ++nc) {
        size_t off = rowoff + colbase + nc * 16;
        float x = xbuf[off];
        float v = vbuf[off];
        float ns = nsbuf[off];
        float m = acc[mr][nc][j] + vt[nc] - v - gii * x;
        node_out[off] = fmaxf(ns + inv * m, 0.f);
      }
    }
  }
}

extern "C" void kernel_launch(void* const* d_in, const int* in_sizes, int n_in,
                              void* d_out, int out_size, void* d_ws, size_t ws_size,
                              hipStream_t stream) {
  const float* node0 = (const float*)d_in[0];
  const int* mask = (const int*)d_in[1];
  const int* graph = (const int*)d_in[2];
  const float* w_weight = (const float*)d_in[3];
  const float* b_weight = (const float*)d_in[4];
  const float* w_self = (const float*)d_in[5];
  const float* b_self = (const float*)d_in[6];
  const float* w_left = (const float*)d_in[7];
  const float* w_right = (const float*)d_in[8];
  float* out = (float*)d_out;
  float* outw = out + (size_t)B * N * D;  // all_node_weight [B,2,N]

  const size_t BND = (size_t)B * N * D;  // 2M elems
  float* f = (float*)d_ws;
  float* xbuf = f;
  float* vbuf = xbuf + BND;
  float* nsbuf = vbuf + BND;
  float* sb = nsbuf + BND;
  float* part = sb + 64;  // padded
  float* vtot = part + (size_t)B * 32 * 128;
  size_t fused = (size_t)(vtot + B * D - f) * sizeof(float);
  fused = (fused + 255) & ~(size_t)255;
  u16* xT = (u16*)((char*)d_ws + fused);
  size_t xt_end = fused + BND * sizeof(u16);
  xt_end = (xt_end + 255) & ~(size_t)255;
  u16* gbf = (u16*)((char*)d_ws + xt_end);
  bool has_gbf = ws_size >= xt_end + (size_t)B * N * N * sizeof(u16);

  mask_sum_kernel<<<B, 256, 0, stream>>>(mask, sb);
  const float* cur = node0;
  for (int t = 0; t < ITERS; ++t) {
    float* nxt = out;  // iter0 writes out-node region as scratch; iter1 overwrites
    prep_kernel<<<B * 32, 256, 0, stream>>>(cur, mask, w_weight, b_weight, w_self,
                                            b_self, w_left, w_right, outw + t * N,
                                            xbuf, vbuf, nsbuf, xT, part);
    vtot_kernel<<<8, 256, 0, stream>>>(part, vtot);
    if (has_gbf) {
      if (t == 0)
        agg_mfma_kernel<0><<<B * 32, 256, 0, stream>>>(graph, gbf, xT, mask, xbuf,
                                                       vbuf, nsbuf, vtot, sb, nxt);
      else
        agg_mfma_kernel<1><<<B * 32, 256, 0, stream>>>(graph, gbf, xT, mask, xbuf,
                                                       vbuf, nsbuf, vtot, sb, nxt);
    } else {
      agg_mfma_kernel<2><<<B * 32, 256, 0, stream>>>(graph, gbf, xT, mask, xbuf,
                                                     vbuf, nsbuf, vtot, sb, nxt);
    }
    cur = nxt;
  }
}

// Round 3
// 126.114 us; speedup vs baseline: 1.6309x; 1.0816x over previous
//
#include <hip/hip_runtime.h>
#include <math.h>

// DigitalGCN: B=16, N=1024, D=128, 2 iters, fp32 in/out.
// out = relu(nsadj + inv*( (G0@x) + Vtot )), nsadj = NS + b_self - inv*v,
//   x = nm*w*(NL-NR), v = nm*w*NR, inv = nm/max(nm*(S-nm),1), G0 = G, diag=0.
// Graph packed to 1 bit/edge (2 MB, diag cleared, per-row byte-permuted for
// MFMA A-frag fetch). All GEMMs on bf16 MFMA, fp32 accumulate.

constexpr int B = 16, N = 1024, D = 128, ITERS = 2;

typedef unsigned short u16;
typedef unsigned char u8;
typedef unsigned int u32;
typedef __attribute__((ext_vector_type(8))) short short8v;
typedef __attribute__((ext_vector_type(4))) float float4v;

__device__ inline u16 f32_to_bf16(float f) {
  u32 bits = __float_as_uint(f);
  bits += 0x7FFFu + ((bits >> 16) & 1u);  // RNE
  return (u16)(bits >> 16);
}

// grid 2052: blocks 0..2047 pack graph bits; 2048..2050 transpose W->bf16;
// 2051 computes per-batch mask sums.
__global__ __launch_bounds__(256) void pack_kernel(
    const int* __restrict__ graph, const int* __restrict__ mask,
    const float* __restrict__ w_self, const float* __restrict__ w_left,
    const float* __restrict__ w_right, u8* __restrict__ gpk, u16* __restrict__ wsT,
    u16* __restrict__ wlT, u16* __restrict__ wrT, float* __restrict__ sb) {
  int blk = blockIdx.x, tid = threadIdx.x;
  if (blk < 2048) {
    int gidx = blk * 256 + tid;  // permuted-dword index, total B*N*32
    int dw = gidx & 31;          // dword within row
    int rowg = gidx >> 5;        // b*N + i
    int i = rowg & (N - 1);
    int lg = dw >> 3;
    int cbase = (dw & 7) * 4;    // 4 chunks per dword
    const int* grow = graph + (size_t)rowg * N;
    u32 word = 0;
#pragma unroll
    for (int m = 0; m < 4; ++m) {
      int c0 = (cbase + m) * 32 + lg * 8;  // 8 source cols
      int4 a = *(const int4*)(grow + c0);
      int4 bb = *(const int4*)(grow + c0 + 4);
      u32 byte = 0;
      byte |= (u32)(a.x != 0) << 0;
      byte |= (u32)(a.y != 0) << 1;
      byte |= (u32)(a.z != 0) << 2;
      byte |= (u32)(a.w != 0) << 3;
      byte |= (u32)(bb.x != 0) << 4;
      byte |= (u32)(bb.y != 0) << 5;
      byte |= (u32)(bb.z != 0) << 6;
      byte |= (u32)(bb.w != 0) << 7;
      if (i >= c0 && i < c0 + 8) byte &= ~(1u << (i - c0));  // clear diagonal
      word |= byte << (m * 8);
    }
    ((u32*)gpk)[gidx] = word;
  } else if (blk < 2051) {
    const float* W = (blk == 2048) ? w_self : (blk == 2049) ? w_left : w_right;
    u16* WT = (blk == 2048) ? wsT : (blk == 2049) ? wlT : wrT;
    for (int e = 0; e < 64; ++e) {
      int o = e * 256 + tid;  // o = c*128 + k
      int c = o >> 7, k = o & 127;
      WT[o] = f32_to_bf16(W[k * 128 + c]);
    }
  } else {
    int b = tid >> 4, seg = tid & 15;
    const int* mp = mask + b * N + seg * 64;
    int s = 0;
    for (int q = 0; q < 64; ++q) s += mp[q];
    float fs = (float)s;
    fs += __shfl_xor(fs, 8, 16);
    fs += __shfl_xor(fs, 4, 16);
    fs += __shfl_xor(fs, 2, 16);
    fs += __shfl_xor(fs, 1, 16);
    if (seg == 0) sb[b] = fs;
  }
}

// prep: 64 rows/block, 512 threads (8 waves: 4 row-groups x 2 col-halves).
// Stages node fp32 in LDS, computes node_weight (fp32), then NS/NL/NR via
// bf16 MFMA; emits nsadj, xT (bf16 transposed), per-block v partials.
__global__ __launch_bounds__(512) void prep_kernel(
    const float* __restrict__ node, const int* __restrict__ mask,
    const float* __restrict__ w_weight, const float* __restrict__ b_weight,
    const float* __restrict__ b_self, const u16* __restrict__ wsT,
    const u16* __restrict__ wlT, const u16* __restrict__ wrT,
    const float* __restrict__ sb, float* __restrict__ outw_t,
    float* __restrict__ nsadj, u16* __restrict__ xT, float* __restrict__ part) {
  __shared__ float nlds[64][132];  // +4 pad: row stride 132 -> 2-way (free)
  __shared__ float wmrow[64];      // w * nm
  __shared__ float invrow[64];     // nm / nnum
  __shared__ float red[4][128];
  int tid = threadIdx.x;
  int b = blockIdx.x >> 4;
  int rt = blockIdx.x & 15;
  int r0 = rt * 64;

  const float* nbase = node + ((size_t)b * N + r0) * D;
#pragma unroll
  for (int p = 0; p < 4; ++p) {
    int g = p * 512 + tid;
    int row = g >> 5, c4 = g & 31;
    *(float4*)&nlds[row][c4 * 4] = *(const float4*)(nbase + row * 128 + c4 * 4);
  }
  __syncthreads();

  {  // node_weight: 8 threads/row, fp32
    int r = tid >> 3, jj = tid & 7;
    float acc = 0.f;
#pragma unroll
    for (int q = 0; q < 4; ++q) {
      float4 wv = *(const float4*)(w_weight + jj * 16 + q * 4);
      const float* np = &nlds[r][jj * 16 + q * 4];
      acc += np[0] * wv.x + np[1] * wv.y + np[2] * wv.z + np[3] * wv.w;
    }
    acc += __shfl_xor(acc, 4, 8);
    acc += __shfl_xor(acc, 2, 8);
    acc += __shfl_xor(acc, 1, 8);
    if (jj == 0) {
      float w = 1.f / (1.f + expf(-(acc + b_weight[0])));
      outw_t[b * (ITERS * N) + r0 + r] = w;
      float nm = (float)mask[b * N + r0 + r];
      float nnum = fmaxf(nm * (sb[b] - nm), 1.f);
      wmrow[r] = w * nm;
      invrow[r] = nm / nnum;
    }
  }
  __syncthreads();

  int w = tid >> 6, lane = tid & 63;
  int l15 = lane & 15, lg = lane >> 4;
  int rw = (w & 3) * 16;   // row group
  int ch = (w >> 2) * 64;  // col half

  short8v af[4];
#pragma unroll
  for (int ks = 0; ks < 4; ++ks) {
    float tmp[8];
    *(float4*)&tmp[0] = *(const float4*)&nlds[rw + l15][ks * 32 + lg * 8];
    *(float4*)&tmp[4] = *(const float4*)&nlds[rw + l15][ks * 32 + lg * 8 + 4];
    short8v t;
#pragma unroll
    for (int e = 0; e < 8; ++e) t[e] = (short)f32_to_bf16(tmp[e]);
    af[ks] = t;
  }

  float4v aNR[4], aNL[4], aNS[4];
#define RUN_GEMM(WT, ACC)                                                       \
  {                                                                             \
    _Pragma("unroll") for (int cf = 0; cf < 4; ++cf) {                          \
      ACC[cf] = (float4v){0.f, 0.f, 0.f, 0.f};                                  \
      const u16* bp = (WT) + (ch + cf * 16 + l15) * 128 + lg * 8;               \
      _Pragma("unroll") for (int ks = 0; ks < 4; ++ks) {                        \
        short8v bf = *(const short8v*)(bp + ks * 32);                           \
        ACC[cf] =                                                               \
            __builtin_amdgcn_mfma_f32_16x16x32_bf16(af[ks], bf, ACC[cf], 0, 0, 0); \
      }                                                                         \
    }                                                                           \
  }
  RUN_GEMM(wrT, aNR);
  RUN_GEMM(wlT, aNL);
  RUN_GEMM(wsT, aNS);
#undef RUN_GEMM

  float wmv[4], invv[4];
  int rows[4];
#pragma unroll
  for (int j = 0; j < 4; ++j) {
    int rloc = rw + lg * 4 + j;
    rows[j] = rloc;
    wmv[j] = wmrow[rloc];
    invv[j] = invrow[rloc];
  }
  float pv[4] = {0.f, 0.f, 0.f, 0.f};
#pragma unroll
  for (int cf = 0; cf < 4; ++cf) {
    int col = ch + cf * 16 + l15;
    float bsv = b_self[col];
    u16 xb[4];
#pragma unroll
    for (int j = 0; j < 4; ++j) {
      float x = wmv[j] * (aNL[cf][j] - aNR[cf][j]);
      float v = wmv[j] * aNR[cf][j];
      pv[cf] += v;
      nsadj[((size_t)b * N + r0 + rows[j]) * D + col] =
          aNS[cf][j] + bsv - invv[j] * v;
      xb[j] = f32_to_bf16(x);
    }
    *(ushort4*)&xT[((size_t)b * D + col) * N + r0 + rw + lg * 4] = *(ushort4*)&xb[0];
  }

#pragma unroll
  for (int cf = 0; cf < 4; ++cf) {
    pv[cf] += __shfl_xor(pv[cf], 16);
    pv[cf] += __shfl_xor(pv[cf], 32);
  }
  if (lg == 0) {
#pragma unroll
    for (int cf = 0; cf < 4; ++cf) red[w & 3][ch + cf * 16 + l15] = pv[cf];
  }
  __syncthreads();
  if (tid < 128) {
    float s = red[0][tid] + red[1][tid] + red[2][tid] + red[3][tid];
    part[((size_t)b * 16 + rt) * 128 + tid] = s;
  }
}

// agg: out = relu(nsadj + inv*(G0@x + Vtot)). 32 rows x 128 cols per block,
// 4 waves (2 row-frags x 2 col-halves), wave tile 16x64. Sync-free main loop:
// A-frags expanded from packed bits via 256-entry LDS LUT.
__global__ __launch_bounds__(256) void agg_kernel(
    const u8* __restrict__ gpk, const u16* __restrict__ xT,
    const int* __restrict__ mask, const float* __restrict__ nsadj,
    const float* __restrict__ part, const float* __restrict__ sb,
    float* __restrict__ out) {
  __shared__ short8v lut[256];
  __shared__ float vt_s[128];
  int tid = threadIdx.x;
  int b = blockIdx.x >> 5;
  int r0 = (blockIdx.x & 31) * 32;
  {
    short8v e;
#pragma unroll
    for (int k = 0; k < 8; ++k) e[k] = ((tid >> k) & 1) ? (short)0x3F80 : (short)0;
    lut[tid] = e;
  }
  if (tid < 128) {
    float s = 0.f;
#pragma unroll
    for (int p = 0; p < 16; ++p) s += part[((size_t)b * 16 + p) * 128 + tid];
    vt_s[tid] = s;
  }
  __syncthreads();

  int w = tid >> 6, lane = tid & 63;
  int l15 = lane & 15, lg = lane >> 4;
  int rf = w >> 1, chh = w & 1;
  int arow = r0 + rf * 16 + l15;
  const u8* gr = gpk + ((size_t)b * N + arow) * 128 + lg * 32;
  uint4 q0 = *(const uint4*)gr;
  uint4 q1 = *(const uint4*)(gr + 16);
  u32 qa[8] = {q0.x, q0.y, q0.z, q0.w, q1.x, q1.y, q1.z, q1.w};

  const u16* xp[4];
#pragma unroll
  for (int cf = 0; cf < 4; ++cf)
    xp[cf] = xT + ((size_t)b * D + chh * 64 + cf * 16 + l15) * N + lg * 8;

  float4v acc[4] = {{0.f, 0.f, 0.f, 0.f},
                    {0.f, 0.f, 0.f, 0.f},
                    {0.f, 0.f, 0.f, 0.f},
                    {0.f, 0.f, 0.f, 0.f}};
#pragma unroll
  for (int cc = 0; cc < 32; ++cc) {
    u32 byte = (qa[cc >> 2] >> ((cc & 3) * 8)) & 255u;
    short8v a = lut[byte];
    int koff = cc * 32;
#pragma unroll
    for (int cf = 0; cf < 4; ++cf) {
      short8v bf = *(const short8v*)(xp[cf] + koff);
      acc[cf] = __builtin_amdgcn_mfma_f32_16x16x32_bf16(a, bf, acc[cf], 0, 0, 0);
    }
  }

  float sbv = sb[b];
#pragma unroll
  for (int j = 0; j < 4; ++j) {
    int orow = r0 + rf * 16 + lg * 4 + j;
    float nm = (float)mask[b * N + orow];
    float nnum = fmaxf(nm * (sbv - nm), 1.f);
    float inv = nm / nnum;
    size_t rowoff = ((size_t)b * N + orow) * D;
#pragma unroll
    for (int cf = 0; cf < 4; ++cf) {
      int col = chh * 64 + cf * 16 + l15;
      float m = acc[cf][j] + vt_s[col];
      out[rowoff + col] = fmaxf(nsadj[rowoff + col] + inv * m, 0.f);
    }
  }
}

extern "C" void kernel_launch(void* const* d_in, const int* in_sizes, int n_in,
                              void* d_out, int out_size, void* d_ws, size_t ws_size,
                              hipStream_t stream) {
  const float* node0 = (const float*)d_in[0];
  const int* mask = (const int*)d_in[1];
  const int* graph = (const int*)d_in[2];
  const float* w_weight = (const float*)d_in[3];
  const float* b_weight = (const float*)d_in[4];
  const float* w_self = (const float*)d_in[5];
  const float* b_self = (const float*)d_in[6];
  const float* w_left = (const float*)d_in[7];
  const float* w_right = (const float*)d_in[8];
  float* out = (float*)d_out;
  float* outw = out + (size_t)B * N * D;  // all_node_weight [B,2,N]

  char* ws = (char*)d_ws;
  float* nsadj = (float*)ws;                                  // 8 MB
  u16* xT = (u16*)(ws + (size_t)8 * 1024 * 1024);             // 4 MB
  u8* gpk = (u8*)(ws + (size_t)12 * 1024 * 1024);             // 2 MB
  u16* wsT = (u16*)(ws + (size_t)14 * 1024 * 1024);           // 3 x 32 KB
  u16* wlT = wsT + 16384;
  u16* wrT = wlT + 16384;
  float* part = (float*)(ws + (size_t)14 * 1024 * 1024 + 3 * 32768);  // 128 KB
  float* sb = part + 16 * 16 * 128;

  pack_kernel<<<2052, 256, 0, stream>>>(graph, mask, w_self, w_left, w_right, gpk,
                                        wsT, wlT, wrT, sb);
  const float* cur = node0;
  for (int t = 0; t < ITERS; ++t) {
    prep_kernel<<<256, 512, 0, stream>>>(cur, mask, w_weight, b_weight, b_self, wsT,
                                         wlT, wrT, sb, outw + t * N, nsadj, xT, part);
    agg_kernel<<<512, 256, 0, stream>>>(gpk, xT, mask, nsadj, part, sb, out);
    cur = out;
  }
}

// Round 4
// 123.319 us; speedup vs baseline: 1.6678x; 1.0227x over previous
//
#include <hip/hip_runtime.h>
#include <math.h>

// DigitalGCN: B=16, N=1024, D=128, 2 iters, fp32 in/out.
// out = relu(nsadj + inv*( (G0@x) + Vtot )), nsadj = NS + b_self - inv*v,
//   x = nm*w*(NL-NR), v = nm*w*NR, inv = nm/max(nm*(S-nm),1), G0 = G diag-cleared.
// Graph packed to 1 bit/edge (2 MB, byte-permuted for MFMA A-frags).
// A-frags expanded bits->bf16 in VALU (no LDS LUT). All GEMMs bf16 MFMA.

constexpr int B = 16, N = 1024, D = 128, ITERS = 2;

typedef unsigned short u16;
typedef unsigned char u8;
typedef unsigned int u32;
typedef __attribute__((ext_vector_type(8))) short short8v;
typedef __attribute__((ext_vector_type(4))) unsigned int uint4v;
typedef __attribute__((ext_vector_type(4))) float float4v;

__device__ inline u16 f32_to_bf16(float f) {
  u32 bits = __float_as_uint(f);
  bits += 0x7FFFu + ((bits >> 16) & 1u);  // RNE
  return (u16)(bits >> 16);
}

// blocks 0..8191: pack 2 graph rows each (coalesced reads, LDS byte shuffle).
// blocks 8192..8194: W transpose to bf16 (LDS 32x32 tiles).
// block 8195: per-batch mask sums.
__global__ __launch_bounds__(256) void pack_kernel(
    const int* __restrict__ graph, const int* __restrict__ mask,
    const float* __restrict__ w_self, const float* __restrict__ w_left,
    const float* __restrict__ w_right, u8* __restrict__ gpk, u16* __restrict__ wsT,
    u16* __restrict__ wlT, u16* __restrict__ wrT, float* __restrict__ sb) {
  int blk = blockIdx.x, tid = threadIdx.x;
  if (blk < 8192) {
    __shared__ u32 lbw[2][32];
    int rl = tid >> 7, j = tid & 127;
    int rowg = blk * 2 + rl;
    int i = rowg & (N - 1);
    const int* gp = graph + (size_t)rowg * N + j * 8;
    int4 a = *(const int4*)gp;
    int4 c = *(const int4*)(gp + 4);
    u32 by = (u32)(a.x != 0) | ((u32)(a.y != 0) << 1) | ((u32)(a.z != 0) << 2) |
             ((u32)(a.w != 0) << 3) | ((u32)(c.x != 0) << 4) |
             ((u32)(c.y != 0) << 5) | ((u32)(c.z != 0) << 6) |
             ((u32)(c.w != 0) << 7);
    if (j == (i >> 3)) by &= ~(1u << (i & 7));  // clear diagonal
    // permuted byte offset: byte[(j&3)*32 + (j>>2)] = cols [j*8, j*8+8)
    ((u8*)&lbw[rl][0])[(j & 3) * 32 + (j >> 2)] = (u8)by;
    __syncthreads();
    if (tid < 64) {
      int rl2 = tid >> 5, d = tid & 31;
      ((u32*)gpk)[(size_t)(blk * 2 + rl2) * 32 + d] = lbw[rl2][d];
    }
  } else if (blk < 8195) {
    __shared__ float tile[32][33];
    const float* W = (blk == 8192) ? w_self : (blk == 8193) ? w_left : w_right;
    u16* WT = (blk == 8192) ? wsT : (blk == 8193) ? wlT : wrT;
    for (int t = 0; t < 16; ++t) {
      int ti = t >> 2, tj = t & 3;
      __syncthreads();
#pragma unroll
      for (int q = 0; q < 4; ++q) {
        int idx = q * 256 + tid;
        int r = idx >> 5, cc = idx & 31;
        tile[r][cc] = W[(ti * 32 + r) * 128 + tj * 32 + cc];
      }
      __syncthreads();
#pragma unroll
      for (int q = 0; q < 4; ++q) {
        int idx = q * 256 + tid;
        int r = idx >> 5, cc = idx & 31;
        WT[(tj * 32 + r) * 128 + ti * 32 + cc] = f32_to_bf16(tile[cc][r]);
      }
    }
  } else {
    int b = tid >> 4, seg = tid & 15;
    const int* mp = mask + b * N + seg * 64;
    int s = 0;
    for (int q = 0; q < 64; ++q) s += mp[q];
    float fs = (float)s;
    fs += __shfl_xor(fs, 8, 16);
    fs += __shfl_xor(fs, 4, 16);
    fs += __shfl_xor(fs, 2, 16);
    fs += __shfl_xor(fs, 1, 16);
    if (seg == 0) sb[b] = fs;
  }
}

// prep: 32 rows/block, 256 threads, 4 waves: (rw in {0,16}) x (ch in {0,64}).
__global__ __launch_bounds__(256) void prep_kernel(
    const float* __restrict__ node, const int* __restrict__ mask,
    const float* __restrict__ w_weight, const float* __restrict__ b_weight,
    const float* __restrict__ b_self, const u16* __restrict__ wsT,
    const u16* __restrict__ wlT, const u16* __restrict__ wrT,
    const float* __restrict__ sb, float* __restrict__ outw_t,
    float* __restrict__ nsadj, u16* __restrict__ xT, float* __restrict__ part) {
  __shared__ float nlds[32][132];
  __shared__ float wmrow[32];
  __shared__ float invrow[32];
  __shared__ float red[2][128];
  int tid = threadIdx.x;
  int b = blockIdx.x >> 5;
  int rt = blockIdx.x & 31;
  int r0 = rt * 32;

  const float* nbase = node + ((size_t)b * N + r0) * D;
#pragma unroll
  for (int p = 0; p < 4; ++p) {
    int g = p * 256 + tid;
    int row = g >> 5, c4 = g & 31;
    *(float4*)&nlds[row][c4 * 4] = *(const float4*)(nbase + row * 128 + c4 * 4);
  }
  __syncthreads();

  {  // node_weight: 8 threads/row, fp32
    int r = tid >> 3, jj = tid & 7;
    float acc = 0.f;
#pragma unroll
    for (int q = 0; q < 4; ++q) {
      float4 wv = *(const float4*)(w_weight + jj * 16 + q * 4);
      const float* np = &nlds[r][jj * 16 + q * 4];
      acc += np[0] * wv.x + np[1] * wv.y + np[2] * wv.z + np[3] * wv.w;
    }
    acc += __shfl_xor(acc, 4, 8);
    acc += __shfl_xor(acc, 2, 8);
    acc += __shfl_xor(acc, 1, 8);
    if (jj == 0) {
      float w = 1.f / (1.f + expf(-(acc + b_weight[0])));
      outw_t[b * (ITERS * N) + r0 + r] = w;
      float nm = (float)mask[b * N + r0 + r];
      float nnum = fmaxf(nm * (sb[b] - nm), 1.f);
      wmrow[r] = w * nm;
      invrow[r] = nm / nnum;
    }
  }
  __syncthreads();

  int w = tid >> 6, lane = tid & 63;
  int l15 = lane & 15, lg = lane >> 4;
  int rw = (w & 1) * 16;
  int ch = (w >> 1) * 64;

  short8v af[4];
#pragma unroll
  for (int ks = 0; ks < 4; ++ks) {
    float tmp[8];
    *(float4*)&tmp[0] = *(const float4*)&nlds[rw + l15][ks * 32 + lg * 8];
    *(float4*)&tmp[4] = *(const float4*)&nlds[rw + l15][ks * 32 + lg * 8 + 4];
    short8v t;
#pragma unroll
    for (int e = 0; e < 8; ++e) t[e] = (short)f32_to_bf16(tmp[e]);
    af[ks] = t;
  }

  float4v aNR[4], aNL[4], aNS[4];
#define RUN_GEMM(WT, ACC)                                                          \
  {                                                                                \
    _Pragma("unroll") for (int cf = 0; cf < 4; ++cf) {                             \
      ACC[cf] = (float4v){0.f, 0.f, 0.f, 0.f};                                     \
      const u16* bp = (WT) + (ch + cf * 16 + l15) * 128 + lg * 8;                  \
      _Pragma("unroll") for (int ks = 0; ks < 4; ++ks) {                           \
        short8v bf = *(const short8v*)(bp + ks * 32);                              \
        ACC[cf] =                                                                  \
            __builtin_amdgcn_mfma_f32_16x16x32_bf16(af[ks], bf, ACC[cf], 0, 0, 0); \
      }                                                                            \
    }                                                                              \
  }
  RUN_GEMM(wrT, aNR);
  RUN_GEMM(wlT, aNL);
  RUN_GEMM(wsT, aNS);
#undef RUN_GEMM

  float wmv[4], invv[4];
  int rows[4];
#pragma unroll
  for (int j = 0; j < 4; ++j) {
    int rloc = rw + lg * 4 + j;
    rows[j] = rloc;
    wmv[j] = wmrow[rloc];
    invv[j] = invrow[rloc];
  }
  float pv[4] = {0.f, 0.f, 0.f, 0.f};
#pragma unroll
  for (int cf = 0; cf < 4; ++cf) {
    int col = ch + cf * 16 + l15;
    float bsv = b_self[col];
    u16 xb[4];
#pragma unroll
    for (int j = 0; j < 4; ++j) {
      float x = wmv[j] * (aNL[cf][j] - aNR[cf][j]);
      float v = wmv[j] * aNR[cf][j];
      pv[cf] += v;
      nsadj[((size_t)b * N + r0 + rows[j]) * D + col] = aNS[cf][j] + bsv - invv[j] * v;
      xb[j] = f32_to_bf16(x);
    }
    *(ushort4*)&xT[((size_t)b * D + col) * N + r0 + rw + lg * 4] = *(ushort4*)&xb[0];
  }

#pragma unroll
  for (int cf = 0; cf < 4; ++cf) {
    pv[cf] += __shfl_xor(pv[cf], 16);
    pv[cf] += __shfl_xor(pv[cf], 32);
  }
  if (lg == 0) {
#pragma unroll
    for (int cf = 0; cf < 4; ++cf) red[w & 1][ch + cf * 16 + l15] = pv[cf];
  }
  __syncthreads();
  if (tid < 128) part[((size_t)b * 32 + rt) * 128 + tid] = red[0][tid] + red[1][tid];
}

// agg: out = relu(nsadj + inv*(G0@x + Vtot)). 32 rows x 128 cols per block,
// 4 waves = (rf in {0,1}) x (ks K-half in {0,1}); wave tile 16 x 128 (cf=8).
// A bits expanded to bf16 in VALU; one expansion feeds 8 MFMAs.
__global__ __launch_bounds__(256) void agg_kernel(
    const u8* __restrict__ gpk, const u16* __restrict__ xT,
    const int* __restrict__ mask, const float* __restrict__ nsadj,
    const float* __restrict__ part, const float* __restrict__ sb,
    float* __restrict__ out) {
  __shared__ float vt_s[128];
  __shared__ float accbuf[2][16][128];  // ks=1 partials, 16 KB
  int tid = threadIdx.x;
  int b = blockIdx.x >> 5;
  int r0 = (blockIdx.x & 31) * 32;
  if (tid < 128) {
    float s = 0.f;
#pragma unroll
    for (int p = 0; p < 32; ++p) s += part[((size_t)b * 32 + p) * 128 + tid];
    vt_s[tid] = s;
  }

  int w = tid >> 6, lane = tid & 63;
  int l15 = lane & 15, lg = lane >> 4;
  int rf = w & 1, ks = w >> 1;
  int arow = r0 + rf * 16 + l15;
  const u8* gr = gpk + ((size_t)b * N + arow) * 128 + lg * 32 + ks * 16;
  uint4 q = *(const uint4*)gr;
  u32 qa[4] = {q.x, q.y, q.z, q.w};

  const u16* xbase = xT + (size_t)b * D * N + (size_t)ks * 512 + lg * 8 +
                     (size_t)l15 * N;

  float4v acc[8] = {{0.f, 0.f, 0.f, 0.f}, {0.f, 0.f, 0.f, 0.f},
                    {0.f, 0.f, 0.f, 0.f}, {0.f, 0.f, 0.f, 0.f},
                    {0.f, 0.f, 0.f, 0.f}, {0.f, 0.f, 0.f, 0.f},
                    {0.f, 0.f, 0.f, 0.f}, {0.f, 0.f, 0.f, 0.f}};
#pragma unroll
  for (int cc = 0; cc < 16; ++cc) {
    u32 by = (qa[cc >> 2] >> ((cc & 3) * 8)) & 255u;
    u32 e0 = ((by & 1u) ? 0x3F80u : 0u) | ((by & 2u) ? 0x3F800000u : 0u);
    u32 e1 = ((by & 4u) ? 0x3F80u : 0u) | ((by & 8u) ? 0x3F800000u : 0u);
    u32 e2 = ((by & 16u) ? 0x3F80u : 0u) | ((by & 32u) ? 0x3F800000u : 0u);
    u32 e3 = ((by & 64u) ? 0x3F80u : 0u) | ((by & 128u) ? 0x3F800000u : 0u);
    uint4v ev = {e0, e1, e2, e3};
    short8v a = __builtin_bit_cast(short8v, ev);
    int koff = cc * 32;
#pragma unroll
    for (int cf = 0; cf < 8; ++cf) {
      short8v bf = *(const short8v*)(xbase + (size_t)cf * 16 * N + koff);
      acc[cf] = __builtin_amdgcn_mfma_f32_16x16x32_bf16(a, bf, acc[cf], 0, 0, 0);
    }
  }

  if (ks == 1) {
#pragma unroll
    for (int cf = 0; cf < 8; ++cf)
#pragma unroll
      for (int j = 0; j < 4; ++j) accbuf[rf][lg * 4 + j][cf * 16 + l15] = acc[cf][j];
  }
  __syncthreads();
  if (ks == 0) {
    float sbv = sb[b];
#pragma unroll
    for (int j = 0; j < 4; ++j) {
      int orow = r0 + rf * 16 + lg * 4 + j;
      float nm = (float)mask[b * N + orow];
      float nnum = fmaxf(nm * (sbv - nm), 1.f);
      float inv = nm / nnum;
      size_t rowoff = ((size_t)b * N + orow) * D;
#pragma unroll
      for (int cf = 0; cf < 8; ++cf) {
        int col = cf * 16 + l15;
        float m = acc[cf][j] + accbuf[rf][lg * 4 + j][col] + vt_s[col];
        out[rowoff + col] = fmaxf(nsadj[rowoff + col] + inv * m, 0.f);
      }
    }
  }
}

extern "C" void kernel_launch(void* const* d_in, const int* in_sizes, int n_in,
                              void* d_out, int out_size, void* d_ws, size_t ws_size,
                              hipStream_t stream) {
  const float* node0 = (const float*)d_in[0];
  const int* mask = (const int*)d_in[1];
  const int* graph = (const int*)d_in[2];
  const float* w_weight = (const float*)d_in[3];
  const float* b_weight = (const float*)d_in[4];
  const float* w_self = (const float*)d_in[5];
  const float* b_self = (const float*)d_in[6];
  const float* w_left = (const float*)d_in[7];
  const float* w_right = (const float*)d_in[8];
  float* out = (float*)d_out;
  float* outw = out + (size_t)B * N * D;  // all_node_weight [B,2,N]

  char* ws = (char*)d_ws;
  float* nsadj = (float*)ws;                                   // 8 MB
  u16* xT = (u16*)(ws + (size_t)8 * 1024 * 1024);              // 4 MB
  u8* gpk = (u8*)(ws + (size_t)12 * 1024 * 1024);              // 2 MB
  u16* wsT = (u16*)(ws + (size_t)14 * 1024 * 1024);            // 3 x 32 KB
  u16* wlT = wsT + 16384;
  u16* wrT = wlT + 16384;
  float* part = (float*)(ws + (size_t)14 * 1024 * 1024 + 3 * 32768);  // 256 KB
  float* sb = part + (size_t)B * 32 * 128;

  pack_kernel<<<8196, 256, 0, stream>>>(graph, mask, w_self, w_left, w_right, gpk,
                                        wsT, wlT, wrT, sb);
  const float* cur = node0;
  for (int t = 0; t < ITERS; ++t) {
    prep_kernel<<<512, 256, 0, stream>>>(cur, mask, w_weight, b_weight, b_self, wsT,
                                         wlT, wrT, sb, outw + t * N, nsadj, xT, part);
    agg_kernel<<<512, 256, 0, stream>>>(gpk, xT, mask, nsadj, part, sb, out);
    cur = out;
  }
}